// Round 11
// baseline (302.142 us; speedup 1.0000x reference)
//
#include <hip/hip_runtime.h>
#include <hip/hip_cooperative_groups.h>
#include <math.h>

namespace cg = cooperative_groups;

#define EPSF 1e-7f

typedef __attribute__((ext_vector_type(4))) float f32x4;
typedef __attribute__((ext_vector_type(8))) short s16x8;

__device__ __forceinline__ unsigned short f2bf(float f) {
    unsigned u = __float_as_uint(f);
    u = (u + 0x7fffu + ((u >> 16) & 1u)) >> 16;
    return (unsigned short)u;
}
__device__ __forceinline__ s16x8 cvt8(const float* p) {
    s16x8 r;
    #pragma unroll
    for (int i = 0; i < 8; ++i) r[i] = (short)f2bf(p[i]);
    return r;
}
__device__ __forceinline__ float wave_reduce_sum(float v) {
    #pragma unroll
    for (int o = 32; o > 0; o >>= 1) v += __shfl_xor(v, o, 64);
    return v;
}

struct MegaArgs {
    const float* x;
    const float* freqs;
    const float* c_sphere;
    const float* W_qkv;
    const float* b_qkv;
    const float* W_out;
    const float* b_out;
    const float* c_logits;
    const float* geo;
    float* out;
    float* qkv;
    unsigned short* qh;
    unsigned short* kh;
    unsigned short* vt;
    unsigned short* aout;
    float* x2q;
    float* y2k;
    unsigned short* P;
};

// One cooperative kernel, 5 phases separated by grid.sync(). Each phase is
// the R10-proven code, grid-strided over its task list.
__global__ __launch_bounds__(256, 4) void k_mega(MegaArgs A) {
    cg::grid_group grid = cg::this_grid();
    const int N = 512;
    int tid = threadIdx.x;
    int wv = tid >> 6, lane = tid & 63, l15 = lane & 15, kb = lane >> 4;
    int NB = gridDim.x;
    int gwave = blockIdx.x * 4 + wv;
    int NW = NB * 4;
    __shared__ float part[16][16];
    __shared__ float sL[16];

    // ---- Phase A: qkv = diag(s_logmap)*(x @ W_qkv) + b. 768 block-tasks,
    // 16x16 MFMA tile per wave, 16-row logmap prologue per task.
    for (int task = blockIdx.x; task < 768; task += NB) {
        int wr = task / 24, cgp = task % 24;
        {
            int row = tid >> 4, seg = tid & 15;
            const float* xr = A.x + (size_t)(wr * 16 + row) * 512 + seg * 32;
            float ss = 0.f;
            #pragma unroll
            for (int i = 0; i < 8; ++i) {
                float4 v = *(const float4*)(xr + i * 4);
                ss += v.x * v.x + v.y * v.y + v.z * v.z + v.w * v.w;
            }
            part[row][seg] = ss;
        }
        __syncthreads();
        if (tid < 16) {
            float ss = 0.f;
            #pragma unroll
            for (int i = 0; i < 16; ++i) ss += part[tid][i];
            float c = A.c_sphere[0];
            float sqc = fmaxf(sqrtf(c), EPSF);
            float yn = sqrtf(ss);
            sL[tid] = (yn < EPSF) ? 0.f
                     : atanhf(fminf(yn, 1.f - EPSF)) / (sqc * fmaxf(yn, EPSF));
        }
        __syncthreads();
        int col0 = cgp * 64 + wv * 16;
        const float* Ab = A.x + (size_t)(wr * 16 + l15) * 512 + kb * 8;
        f32x4 acc = {};
        #pragma unroll 4
        for (int k0 = 0; k0 < 512; k0 += 32) {
            s16x8 a = cvt8(Ab + k0);
            s16x8 b;
            #pragma unroll
            for (int t = 0; t < 8; ++t)
                b[t] = (short)f2bf(A.W_qkv[(size_t)(k0 + kb * 8 + t) * 1536 + col0 + l15]);
            acc = __builtin_amdgcn_mfma_f32_16x16x32_bf16(a, b, acc, 0, 0, 0);
        }
        int col = col0 + l15;
        float bv = A.b_qkv[col];
        #pragma unroll
        for (int r = 0; r < 4; ++r) {
            int row_l = kb * 4 + r;
            A.qkv[(size_t)(wr * 16 + row_l) * 1536 + col] = acc[r] * sL[row_l] + bv;
        }
        __syncthreads();
    }
    grid.sync();

    // ---- Phase B: RoPE + expmap0 + relayouts. 4096 wave-tasks (h,n).
    for (int vec = gwave; vec < 4096; vec += NW) {
        int h = vec >> 9;
        int n = vec & 511;
        float c = log1pf(expf(A.c_logits[h]));
        float sqc = fmaxf(sqrtf(c), EPSF);
        int j = lane & 31;
        float f = A.freqs[n * 32 + j];
        float cs = cosf(f), sn = sinf(f);
        const float* base = A.qkv + (size_t)n * 1536;
        size_t oidx = ((size_t)h * N + n) * 64 + lane;
        {
            float qa = base[h * 64 + lane];
            float qb = base[h * 64 + (lane ^ 32)];
            float qr = (lane < 32) ? (qa * cs - qb * sn) : (qa * cs + qb * sn);
            float vn2 = wave_reduce_sum(qr * qr);
            float vn = sqrtf(vn2);
            float scale, fn;
            if (vn < EPSF) { scale = 0.f; fn = 0.f; }
            else {
                float mag = tanhf(sqc * vn) / sqc;
                scale = mag / fmaxf(vn, EPSF);
                fn = mag;
                if (fn >= 1.f) { scale *= (1.f - EPSF) / fn; fn = 1.f - EPSF; }
            }
            A.qh[oidx] = f2bf(qr * scale);
            if (lane == 0) A.x2q[h * N + n] = fn * fn;
        }
        {
            float ka = base[512 + h * 64 + lane];
            float kb2 = base[512 + h * 64 + (lane ^ 32)];
            float kr = (lane < 32) ? (ka * cs - kb2 * sn) : (ka * cs + kb2 * sn);
            float vn2 = wave_reduce_sum(kr * kr);
            float vn = sqrtf(vn2);
            float scale, fn;
            if (vn < EPSF) { scale = 0.f; fn = 0.f; }
            else {
                float mag = tanhf(sqc * vn) / sqc;
                scale = mag / fmaxf(vn, EPSF);
                fn = mag;
                if (fn >= 1.f) { scale *= (1.f - EPSF) / fn; fn = 1.f - EPSF; }
            }
            A.kh[oidx] = f2bf(kr * scale);
            if (lane == 0) A.y2k[h * N + n] = fn * fn;
        }
        A.vt[((size_t)h * 64 + lane) * N + n] = f2bf(base[1024 + h * 64 + lane]);
    }
    grid.sync();

    // ---- Phase C: QK^T + hyperbolic dist + exp -> P. 1152 wave-tasks
    // (8 heads x 36 lower-tri 64-tiles x 4 quadrants of 32x32).
    for (int t = gwave; t < 1152; t += NW) {
        int h = t / 144;
        int rem = t % 144;
        int p = rem >> 2, quad = rem & 3;
        int wr_ = quad >> 1, wc_ = quad & 1;
        int qt = 0;
        while ((qt + 1) * (qt + 2) / 2 <= p) qt++;
        int kt = p - qt * (qt + 1) / 2;
        int qrow0 = qt * 64 + wr_ * 32, kcol0 = kt * 64 + wc_ * 32;
        const unsigned short* qb = A.qh + ((size_t)h * N + qrow0 + l15) * 64 + kb * 8;
        const unsigned short* kb_ = A.kh + ((size_t)h * N + kcol0 + l15) * 64 + kb * 8;
        f32x4 acc[2][2] = {};
        #pragma unroll
        for (int kk = 0; kk < 2; ++kk) {
            s16x8 a0 = *(const s16x8*)(qb + kk * 32);
            s16x8 a1 = *(const s16x8*)(qb + 16 * 64 + kk * 32);
            s16x8 b0 = *(const s16x8*)(kb_ + kk * 32);
            s16x8 b1 = *(const s16x8*)(kb_ + 16 * 64 + kk * 32);
            acc[0][0] = __builtin_amdgcn_mfma_f32_16x16x32_bf16(a0, b0, acc[0][0], 0, 0, 0);
            acc[0][1] = __builtin_amdgcn_mfma_f32_16x16x32_bf16(a0, b1, acc[0][1], 0, 0, 0);
            acc[1][0] = __builtin_amdgcn_mfma_f32_16x16x32_bf16(a1, b0, acc[1][0], 0, 0, 0);
            acc[1][1] = __builtin_amdgcn_mfma_f32_16x16x32_bf16(a1, b1, acc[1][1], 0, 0, 0);
        }
        float c = log1pf(expf(A.c_logits[h]));
        float sqc = fmaxf(sqrtf(c), EPSF);
        float gs = A.geo[h];
        #pragma unroll
        for (int mi = 0; mi < 2; ++mi)
            #pragma unroll
            for (int r = 0; r < 4; ++r) {
                int qi = qrow0 + mi * 16 + kb * 4 + r;
                float x2 = A.x2q[h * N + qi];
                float b_ = 1.f - c * x2;
                #pragma unroll
                for (int ni = 0; ni < 2; ++ni) {
                    int ki = kcol0 + ni * 16 + l15;
                    float y2 = A.y2k[h * N + ki];
                    float dot = acc[mi][ni][r];
                    float a_ = 1.f + c * (y2 - 2.f * dot);
                    float num2 = a_ * a_ * x2 + b_ * b_ * y2 - 2.f * a_ * b_ * dot;
                    float den = fmaxf(1.f - 2.f * c * dot + c * c * x2 * y2, EPSF);
                    float nrm = sqrtf(fmaxf(num2, 0.f)) / den;
                    if (nrm >= 1.f) nrm = 1.f - EPSF;
                    float arg = fminf(sqc * nrm, 1.f - EPSF);
                    float s = -gs * (2.f * atanhf(arg) / sqc);
                    float pe = (ki <= qi) ? expf(s) : 0.f;
                    A.P[((size_t)(h * N + qi)) * N + ki] = f2bf(pe);
                }
            }
    }
    grid.sync();

    // ---- Phase D: O = P@V (16x16 tiles) + ones-MFMA row-sum. 1024 wave-tasks
    // (32 row-tiles x 8 heads x 4 d-tiles).
    s16x8 ones;
    #pragma unroll
    for (int i = 0; i < 8; ++i) ones[i] = (short)0x3F80;   // bf16 1.0
    for (int t = gwave; t < 1024; t += NW) {
        int rt = t >> 5;
        int rem = t & 31;
        int h = rem >> 2, dt = rem & 3;
        int r0 = rt * 16, d0 = dt * 16;
        const unsigned short* Pb = A.P + ((size_t)(h * N + r0 + l15)) * N + kb * 8;
        const unsigned short* Vb = A.vt + ((size_t)(h * 64 + d0 + l15)) * N + kb * 8;
        f32x4 acc = {};
        f32x4 acc_s = {};
        int kend = r0 + 16;
        for (int k0 = 0; k0 < kend; k0 += 32) {
            s16x8 a = *(const s16x8*)(Pb + k0);
            s16x8 b = *(const s16x8*)(Vb + k0);
            acc = __builtin_amdgcn_mfma_f32_16x16x32_bf16(a, b, acc, 0, 0, 0);
            acc_s = __builtin_amdgcn_mfma_f32_16x16x32_bf16(a, ones, acc_s, 0, 0, 0);
        }
        #pragma unroll
        for (int r = 0; r < 4; ++r) {
            int qi = r0 + kb * 4 + r;
            float il = 1.f / acc_s[r];
            A.aout[(size_t)qi * 512 + h * 64 + d0 + l15] = f2bf(acc[r] * il);
        }
    }
    grid.sync();

    // ---- Phase E: out = aout @ W_out + b. 1024 wave-tasks of 16x16.
    for (int t = gwave; t < 1024; t += NW) {
        int wr_ = t >> 5;
        int ct = t & 31;
        int col0 = ct * 16;
        const unsigned short* Ab = A.aout + (size_t)(wr_ * 16 + l15) * 512 + kb * 8;
        f32x4 acc = {};
        #pragma unroll 4
        for (int k0 = 0; k0 < 512; k0 += 32) {
            s16x8 a = *(const s16x8*)(Ab + k0);
            s16x8 b;
            #pragma unroll
            for (int tt = 0; tt < 8; ++tt)
                b[tt] = (short)f2bf(A.W_out[(size_t)(k0 + kb * 8 + tt) * 512 + col0 + l15]);
            acc = __builtin_amdgcn_mfma_f32_16x16x32_bf16(a, b, acc, 0, 0, 0);
        }
        int col = col0 + l15;
        float bv = A.b_out[col];
        #pragma unroll
        for (int r = 0; r < 4; ++r)
            A.out[(size_t)(wr_ * 16 + kb * 4 + r) * 512 + col] = acc[r] + bv;
    }
}

extern "C" void kernel_launch(void* const* d_in, const int* in_sizes, int n_in,
                              void* d_out, int out_size, void* d_ws, size_t ws_size,
                              hipStream_t stream) {
    MegaArgs A;
    A.x        = (const float*)d_in[0];
    A.freqs    = (const float*)d_in[1];
    A.c_sphere = (const float*)d_in[2];
    A.W_qkv    = (const float*)d_in[3];
    A.b_qkv    = (const float*)d_in[4];
    A.W_out    = (const float*)d_in[5];
    A.b_out    = (const float*)d_in[6];
    A.c_logits = (const float*)d_in[7];
    A.geo      = (const float*)d_in[8];
    A.out      = (float*)d_out;

    char* base = (char*)d_ws;
    A.qkv  = (float*)base;              base += 3 * 1024 * 1024;
    A.qh   = (unsigned short*)base;     base += 512 * 1024;
    A.kh   = (unsigned short*)base;     base += 512 * 1024;
    A.vt   = (unsigned short*)base;     base += 512 * 1024;
    A.aout = (unsigned short*)base;     base += 512 * 1024;
    A.x2q  = (float*)base;              base += 16 * 1024;
    A.y2k  = (float*)base;              base += 16 * 1024;
    A.P    = (unsigned short*)base;     base += 4 * 1024 * 1024;

    int maxB = 0;
    if (hipOccupancyMaxActiveBlocksPerMultiprocessor(&maxB, k_mega, 256, 0) != hipSuccess
        || maxB < 1)
        maxB = 1;
    unsigned grid = (unsigned)maxB * 256u;
    if (grid > 1024u) grid = 1024u;

    void* args[] = { &A };
    hipLaunchCooperativeKernel((const void*)k_mega, dim3(grid), dim3(256),
                               args, 0, stream);
}

// Round 12
// 59.276 us; speedup vs baseline: 5.0972x; 5.0972x over previous
//
#include <hip/hip_runtime.h>
#include <math.h>

#define EPSF 1e-7f

typedef __attribute__((ext_vector_type(4))) float f32x4;
typedef __attribute__((ext_vector_type(8))) short s16x8;

__device__ __forceinline__ unsigned short f2bf(float f) {
    unsigned u = __float_as_uint(f);
    u = (u + 0x7fffu + ((u >> 16) & 1u)) >> 16;
    return (unsigned short)u;
}
__device__ __forceinline__ s16x8 cvt8(const float* p) {
    s16x8 r;
    #pragma unroll
    for (int i = 0; i < 8; ++i) r[i] = (short)f2bf(p[i]);
    return r;
}

// K1: fused logmap + QKV GEMM + RoPE + expmap0.
// Block = (16-row tile rt, head h): 256 blocks, 4 waves.
// GEMM: wave wv computes 16x16 tiles of q,k,v at head-cols wv*16 (3 MFMA
// chains sharing the A fragment). q,k -> LDS (fp32); v -> vt directly.
// RoPE: each wave handles 4 vectors IN PARALLEL via 16-lane groups (lane
// owns elements j, j+16, j+32, j+48; both rope partners in-lane; norm
// reduce = shfl_xor 1/2/4/8 within the group). No serial vector loop.
__global__ __launch_bounds__(256, 4) void k_qkv_rope(
        const float* __restrict__ x, const float* __restrict__ W,
        const float* __restrict__ bias, const float* __restrict__ c_sphere,
        const float* __restrict__ freqs, const float* __restrict__ c_logits,
        unsigned short* __restrict__ qh, unsigned short* __restrict__ kh,
        unsigned short* __restrict__ vt,
        float* __restrict__ x2q, float* __restrict__ y2k) {
    const int K = 512, NN = 1536, N = 512;
    int b = blockIdx.x;
    int rt = b >> 3, h = b & 7;
    int n0 = rt * 16;
    int tid = threadIdx.x;
    int wv = tid >> 6, lane = tid & 63, l15 = lane & 15, kb = lane >> 4;
    __shared__ float part[16][16];
    __shared__ float sL[16];
    __shared__ float pq[16][65];
    __shared__ float pk[16][65];

    {   // logmap prologue: ||x_row||^2 for rows n0..n0+15
        int row = tid >> 4, seg = tid & 15;
        const float* xr = x + (size_t)(n0 + row) * K + seg * 32;
        float ss = 0.f;
        #pragma unroll
        for (int i = 0; i < 8; ++i) {
            float4 v = *(const float4*)(xr + i * 4);
            ss += v.x * v.x + v.y * v.y + v.z * v.z + v.w * v.w;
        }
        part[row][seg] = ss;
    }
    __syncthreads();
    if (tid < 16) {
        float ss = 0.f;
        #pragma unroll
        for (int i = 0; i < 16; ++i) ss += part[tid][i];
        float c = c_sphere[0];
        float sqc = fmaxf(sqrtf(c), EPSF);
        float yn = sqrtf(ss);
        sL[tid] = (yn < EPSF) ? 0.f
                 : atanhf(fminf(yn, 1.f - EPSF)) / (sqc * fmaxf(yn, EPSF));
    }
    __syncthreads();

    // GEMM: three 16x16 tiles (q,k,v), shared A fragment.
    int cq = h * 64 + wv * 16 + l15;        // q col
    const float* Ab = x + (size_t)(n0 + l15) * K + kb * 8;
    f32x4 accq = {}, acck = {}, accv = {};
    #pragma unroll 4
    for (int k0 = 0; k0 < K; k0 += 32) {
        s16x8 a = cvt8(Ab + k0);
        s16x8 bq, bk, bv;
        #pragma unroll
        for (int t = 0; t < 8; ++t) {
            const float* wp = W + (size_t)(k0 + kb * 8 + t) * NN + cq;
            bq[t] = (short)f2bf(wp[0]);
            bk[t] = (short)f2bf(wp[512]);
            bv[t] = (short)f2bf(wp[1024]);
        }
        accq = __builtin_amdgcn_mfma_f32_16x16x32_bf16(a, bq, accq, 0, 0, 0);
        acck = __builtin_amdgcn_mfma_f32_16x16x32_bf16(a, bk, acck, 0, 0, 0);
        accv = __builtin_amdgcn_mfma_f32_16x16x32_bf16(a, bv, accv, 0, 0, 0);
    }
    {
        float bq_ = bias[cq], bk_ = bias[512 + cq], bv_ = bias[1024 + cq];
        int d = wv * 16 + l15;
        #pragma unroll
        for (int r = 0; r < 4; ++r) {
            int row_l = kb * 4 + r;
            float sc = sL[row_l];
            pq[row_l][d] = accq[r] * sc + bq_;
            pk[row_l][d] = acck[r] * sc + bk_;
            float vval = accv[r] * sc + bv_;
            vt[((size_t)(h * 64 + d)) * N + n0 + row_l] = f2bf(vval);
        }
    }
    __syncthreads();

    // RoPE + expmap: 16 vectors; wave wv owns vectors wv*4+kb (4 parallel
    // 16-lane groups). Lane handles j = l15, l15+16, l15+32, l15+48.
    int row_l = wv * 4 + kb;
    int n = n0 + row_l;
    float c = log1pf(expf(c_logits[h]));
    float sqc = fmaxf(sqrtf(c), EPSF);
    float f1 = freqs[n * 32 + l15];
    float f2 = freqs[n * 32 + l15 + 16];
    float c1 = cosf(f1), s1 = sinf(f1), c2 = cosf(f2), s2 = sinf(f2);
    size_t obase = ((size_t)h * N + n) * 64;
    #pragma unroll
    for (int qk = 0; qk < 2; ++qk) {
        const float (*P)[65] = qk ? pk : pq;
        float a1 = P[row_l][l15],      b1 = P[row_l][l15 + 32];
        float a2 = P[row_l][l15 + 16], b2 = P[row_l][l15 + 48];
        float o0 = a1 * c1 - b1 * s1;     // j = l15
        float o1 = a2 * c2 - b2 * s2;     // j = l15+16
        float o2 = a1 * s1 + b1 * c1;     // j = l15+32
        float o3 = a2 * s2 + b2 * c2;     // j = l15+48
        float loc = o0 * o0 + o1 * o1 + o2 * o2 + o3 * o3;
        #pragma unroll
        for (int xo = 1; xo < 16; xo <<= 1) loc += __shfl_xor(loc, xo, 64);
        float vn = sqrtf(loc);
        float scale, fn;
        if (vn < EPSF) { scale = 0.f; fn = 0.f; }
        else {
            float mag = tanhf(sqc * vn) / sqc;
            scale = mag / fmaxf(vn, EPSF);
            fn = mag;
            if (fn >= 1.f) { scale *= (1.f - EPSF) / fn; fn = 1.f - EPSF; }
        }
        unsigned short* outp = (qk ? kh : qh) + obase;
        outp[l15]      = f2bf(o0 * scale);
        outp[l15 + 16] = f2bf(o1 * scale);
        outp[l15 + 32] = f2bf(o2 * scale);
        outp[l15 + 48] = f2bf(o3 * scale);
        if (l15 == 0) (qk ? y2k : x2q)[h * N + n] = fn * fn;
    }
}

// K2: QK^T via MFMA per lower-triangular (h, 64x64 tile); epilogue computes
// hyperbolic dist + causal mask + exp -> P(bf16). 288 blocks.
__global__ __launch_bounds__(256, 4) void k_qkt_mfma(
        const unsigned short* __restrict__ qh, const unsigned short* __restrict__ kh,
        const float* __restrict__ x2q, const float* __restrict__ y2k,
        const float* __restrict__ c_logits, const float* __restrict__ geo_scale,
        unsigned short* __restrict__ P) {
    const int N = 512;
    int p = blockIdx.x, h = blockIdx.y;
    int qt = 0;
    while ((qt + 1) * (qt + 2) / 2 <= p) qt++;
    int kt = p - qt * (qt + 1) / 2;
    int tid = threadIdx.x, lane = tid & 63, wv = tid >> 6;
    int wr = wv >> 1, wc = wv & 1;
    int l15 = lane & 15, kb = lane >> 4;
    int qrow0 = qt * 64 + wr * 32, kcol0 = kt * 64 + wc * 32;
    const unsigned short* qb = qh + ((size_t)h * N + qrow0 + l15) * 64 + kb * 8;
    const unsigned short* kb_ = kh + ((size_t)h * N + kcol0 + l15) * 64 + kb * 8;
    f32x4 acc[2][2] = {};
    #pragma unroll
    for (int kk = 0; kk < 2; ++kk) {
        s16x8 a0 = *(const s16x8*)(qb + kk * 32);
        s16x8 a1 = *(const s16x8*)(qb + 16 * 64 + kk * 32);
        s16x8 b0 = *(const s16x8*)(kb_ + kk * 32);
        s16x8 b1 = *(const s16x8*)(kb_ + 16 * 64 + kk * 32);
        acc[0][0] = __builtin_amdgcn_mfma_f32_16x16x32_bf16(a0, b0, acc[0][0], 0, 0, 0);
        acc[0][1] = __builtin_amdgcn_mfma_f32_16x16x32_bf16(a0, b1, acc[0][1], 0, 0, 0);
        acc[1][0] = __builtin_amdgcn_mfma_f32_16x16x32_bf16(a1, b0, acc[1][0], 0, 0, 0);
        acc[1][1] = __builtin_amdgcn_mfma_f32_16x16x32_bf16(a1, b1, acc[1][1], 0, 0, 0);
    }
    float c = log1pf(expf(c_logits[h]));
    float sqc = fmaxf(sqrtf(c), EPSF);
    float gs = geo_scale[h];
    #pragma unroll
    for (int mi = 0; mi < 2; ++mi)
        #pragma unroll
        for (int r = 0; r < 4; ++r) {
            int qi = qrow0 + mi * 16 + kb * 4 + r;
            float x2 = x2q[h * N + qi];
            float b_ = 1.f - c * x2;
            #pragma unroll
            for (int ni = 0; ni < 2; ++ni) {
                int ki = kcol0 + ni * 16 + l15;
                float y2 = y2k[h * N + ki];
                float dot = acc[mi][ni][r];
                float a_ = 1.f + c * (y2 - 2.f * dot);
                float num2 = a_ * a_ * x2 + b_ * b_ * y2 - 2.f * a_ * b_ * dot;
                float den = fmaxf(1.f - 2.f * c * dot + c * c * x2 * y2, EPSF);
                float nrm = sqrtf(fmaxf(num2, 0.f)) / den;
                if (nrm >= 1.f) nrm = 1.f - EPSF;
                float arg = fminf(sqc * nrm, 1.f - EPSF);
                float s = -gs * (2.f * atanhf(arg) / sqc);
                float pe = (ki <= qi) ? expf(s) : 0.f;
                P[((size_t)(h * N + qi)) * N + ki] = f2bf(pe);
            }
        }
}

// K3: O = P @ V via MFMA, 16x16 tiles. Row-sum via extra MFMA against an
// all-ones B fragment. Grid (32 row-tiles, 8 heads).
__global__ __launch_bounds__(256, 4) void k_pv_mfma(
        const unsigned short* __restrict__ P, const unsigned short* __restrict__ vt,
        unsigned short* __restrict__ aout) {
    const int N = 512;
    int rt = blockIdx.x, h = blockIdx.y;
    int tid = threadIdx.x, lane = tid & 63, wv = tid >> 6;
    int l15 = lane & 15, kb = lane >> 4;
    int r0 = rt * 16;
    int d0 = wv * 16;
    s16x8 ones;
    #pragma unroll
    for (int i = 0; i < 8; ++i) ones[i] = (short)0x3F80;   // bf16 1.0
    const unsigned short* Pb = P + ((size_t)(h * N + r0 + l15)) * N + kb * 8;
    const unsigned short* Vb = vt + ((size_t)(h * 64 + d0 + l15)) * N + kb * 8;
    f32x4 acc = {};
    f32x4 acc_s = {};
    int kend = r0 + 16;
    for (int k0 = 0; k0 < kend; k0 += 32) {
        s16x8 a = *(const s16x8*)(Pb + k0);
        s16x8 b = *(const s16x8*)(Vb + k0);
        acc = __builtin_amdgcn_mfma_f32_16x16x32_bf16(a, b, acc, 0, 0, 0);
        acc_s = __builtin_amdgcn_mfma_f32_16x16x32_bf16(a, ones, acc_s, 0, 0, 0);
    }
    #pragma unroll
    for (int r = 0; r < 4; ++r) {
        int qi = r0 + kb * 4 + r;
        float il = 1.f / acc_s[r];
        aout[(size_t)qi * 512 + h * 64 + d0 + l15] = f2bf(acc[r] * il);
    }
}

// K4: out = aout(bf16) @ W_out + b. 16x16 tiles, W gathered fp32->bf16.
__global__ __launch_bounds__(256, 4) void k_out(
        const unsigned short* __restrict__ A, const float* __restrict__ W,
        const float* __restrict__ bias, float* __restrict__ C) {
    const int K = 512, NN = 512;
    int tid = threadIdx.x;
    int wv = tid >> 6, lane = tid & 63, l15 = lane & 15, kb = lane >> 4;
    int wr = blockIdx.x / 8;
    int cg = blockIdx.x % 8;
    int col0 = cg * 64 + wv * 16;
    const unsigned short* Ab = A + (size_t)(wr * 16 + l15) * K + kb * 8;
    f32x4 acc = {};
    #pragma unroll 4
    for (int k0 = 0; k0 < K; k0 += 32) {
        s16x8 a = *(const s16x8*)(Ab + k0);
        s16x8 b;
        #pragma unroll
        for (int t = 0; t < 8; ++t)
            b[t] = (short)f2bf(W[(size_t)(k0 + kb * 8 + t) * NN + col0 + l15]);
        acc = __builtin_amdgcn_mfma_f32_16x16x32_bf16(a, b, acc, 0, 0, 0);
    }
    int col = col0 + l15;
    float bv = bias[col];
    #pragma unroll
    for (int r = 0; r < 4; ++r)
        C[(size_t)(wr * 16 + kb * 4 + r) * NN + col] = acc[r] + bv;
}

extern "C" void kernel_launch(void* const* d_in, const int* in_sizes, int n_in,
                              void* d_out, int out_size, void* d_ws, size_t ws_size,
                              hipStream_t stream) {
    const float* x_hyp     = (const float*)d_in[0];
    const float* freqs     = (const float*)d_in[1];
    const float* c_sphere  = (const float*)d_in[2];
    const float* w_qkv     = (const float*)d_in[3];
    const float* b_qkv     = (const float*)d_in[4];
    const float* w_out     = (const float*)d_in[5];
    const float* b_out     = (const float*)d_in[6];
    const float* c_logits  = (const float*)d_in[7];
    const float* geo_scale = (const float*)d_in[8];
    float* out = (float*)d_out;

    const int H = 8;
    char* base = (char*)d_ws;
    unsigned short* qh16   = (unsigned short*)base;    base += 512 * 1024;
    unsigned short* kh16   = (unsigned short*)base;    base += 512 * 1024;
    unsigned short* vt16   = (unsigned short*)base;    base += 512 * 1024;
    unsigned short* aout16 = (unsigned short*)base;    base += 512 * 1024;
    float*          x2q    = (float*)base;             base += 16 * 1024;
    float*          y2k    = (float*)base;             base += 16 * 1024;
    unsigned short* P16    = (unsigned short*)base;    base += 4 * 1024 * 1024;

    k_qkv_rope<<<256, 256, 0, stream>>>(x_hyp, w_qkv, b_qkv, c_sphere, freqs,
                                        c_logits, qh16, kh16, vt16, x2q, y2k);
    k_qkt_mfma<<<dim3(36, H), 256, 0, stream>>>(qh16, kh16, x2q, y2k,
                                                c_logits, geo_scale, P16);
    k_pv_mfma<<<dim3(32, H), 256, 0, stream>>>(P16, vt16, aout16);
    k_out<<<256, 256, 0, stream>>>(aout16, w_out, b_out, out);
}

// Round 14
// 49.780 us; speedup vs baseline: 6.0696x; 1.1908x over previous
//
#include <hip/hip_runtime.h>
#include <math.h>

#define EPSF 1e-7f

typedef __attribute__((ext_vector_type(4))) float f32x4;
typedef __attribute__((ext_vector_type(8))) short s16x8;

__device__ __forceinline__ unsigned short f2bf(float f) {
    unsigned u = __float_as_uint(f);
    u = (u + 0x7fffu + ((u >> 16) & 1u)) >> 16;
    return (unsigned short)u;
}
__device__ __forceinline__ s16x8 cvt8(const float* p) {
    s16x8 r;
    #pragma unroll
    for (int i = 0; i < 8; ++i) r[i] = (short)f2bf(p[i]);
    return r;
}

// K1: fused logmap + QKV GEMM + RoPE + expmap0 (R12-proven).
__global__ __launch_bounds__(256, 4) void k_qkv_rope(
        const float* __restrict__ x, const float* __restrict__ W,
        const float* __restrict__ bias, const float* __restrict__ c_sphere,
        const float* __restrict__ freqs, const float* __restrict__ c_logits,
        unsigned short* __restrict__ qh, unsigned short* __restrict__ kh,
        unsigned short* __restrict__ vt,
        float* __restrict__ x2q, float* __restrict__ y2k) {
    const int K = 512, NN = 1536, N = 512;
    int b = blockIdx.x;
    int rt = b >> 3, h = b & 7;
    int n0 = rt * 16;
    int tid = threadIdx.x;
    int wv = tid >> 6, lane = tid & 63, l15 = lane & 15, kb = lane >> 4;
    __shared__ float part[16][16];
    __shared__ float sL[16];
    __shared__ float pq[16][65];
    __shared__ float pk[16][65];

    {   // logmap prologue
        int row = tid >> 4, seg = tid & 15;
        const float* xr = x + (size_t)(n0 + row) * K + seg * 32;
        float ss = 0.f;
        #pragma unroll
        for (int i = 0; i < 8; ++i) {
            float4 v = *(const float4*)(xr + i * 4);
            ss += v.x * v.x + v.y * v.y + v.z * v.z + v.w * v.w;
        }
        part[row][seg] = ss;
    }
    __syncthreads();
    if (tid < 16) {
        float ss = 0.f;
        #pragma unroll
        for (int i = 0; i < 16; ++i) ss += part[tid][i];
        float c = c_sphere[0];
        float sqc = fmaxf(sqrtf(c), EPSF);
        float yn = sqrtf(ss);
        sL[tid] = (yn < EPSF) ? 0.f
                 : atanhf(fminf(yn, 1.f - EPSF)) / (sqc * fmaxf(yn, EPSF));
    }
    __syncthreads();

    int cq = h * 64 + wv * 16 + l15;
    const float* Ab = x + (size_t)(n0 + l15) * K + kb * 8;
    f32x4 accq = {}, acck = {}, accv = {};
    #pragma unroll 4
    for (int k0 = 0; k0 < K; k0 += 32) {
        s16x8 a = cvt8(Ab + k0);
        s16x8 bq, bk, bv;
        #pragma unroll
        for (int t = 0; t < 8; ++t) {
            const float* wp = W + (size_t)(k0 + kb * 8 + t) * NN + cq;
            bq[t] = (short)f2bf(wp[0]);
            bk[t] = (short)f2bf(wp[512]);
            bv[t] = (short)f2bf(wp[1024]);
        }
        accq = __builtin_amdgcn_mfma_f32_16x16x32_bf16(a, bq, accq, 0, 0, 0);
        acck = __builtin_amdgcn_mfma_f32_16x16x32_bf16(a, bk, acck, 0, 0, 0);
        accv = __builtin_amdgcn_mfma_f32_16x16x32_bf16(a, bv, accv, 0, 0, 0);
    }
    {
        float bq_ = bias[cq], bk_ = bias[512 + cq], bv_ = bias[1024 + cq];
        int d = wv * 16 + l15;
        #pragma unroll
        for (int r = 0; r < 4; ++r) {
            int row_l = kb * 4 + r;
            float sc = sL[row_l];
            pq[row_l][d] = accq[r] * sc + bq_;
            pk[row_l][d] = acck[r] * sc + bk_;
            float vval = accv[r] * sc + bv_;
            vt[((size_t)(h * 64 + d)) * N + n0 + row_l] = f2bf(vval);
        }
    }
    __syncthreads();

    // RoPE + expmap: 4 vectors per wave in parallel (16-lane groups).
    int row_l = wv * 4 + kb;
    int n = n0 + row_l;
    float c = log1pf(expf(c_logits[h]));
    float sqc = fmaxf(sqrtf(c), EPSF);
    float f1 = freqs[n * 32 + l15];
    float f2 = freqs[n * 32 + l15 + 16];
    float c1 = cosf(f1), s1 = sinf(f1), c2 = cosf(f2), s2 = sinf(f2);
    size_t obase = ((size_t)h * N + n) * 64;
    #pragma unroll
    for (int qk = 0; qk < 2; ++qk) {
        const float (*P)[65] = qk ? pk : pq;
        float a1 = P[row_l][l15],      b1 = P[row_l][l15 + 32];
        float a2 = P[row_l][l15 + 16], b2 = P[row_l][l15 + 48];
        float o0 = a1 * c1 - b1 * s1;
        float o1 = a2 * c2 - b2 * s2;
        float o2 = a1 * s1 + b1 * c1;
        float o3 = a2 * s2 + b2 * c2;
        float loc = o0 * o0 + o1 * o1 + o2 * o2 + o3 * o3;
        #pragma unroll
        for (int xo = 1; xo < 16; xo <<= 1) loc += __shfl_xor(loc, xo, 64);
        float vn = sqrtf(loc);
        float scale, fn;
        if (vn < EPSF) { scale = 0.f; fn = 0.f; }
        else {
            float mag = tanhf(sqc * vn) / sqc;
            scale = mag / fmaxf(vn, EPSF);
            fn = mag;
            if (fn >= 1.f) { scale *= (1.f - EPSF) / fn; fn = 1.f - EPSF; }
        }
        unsigned short* outp = (qk ? kh : qh) + obase;
        outp[l15]      = f2bf(o0 * scale);
        outp[l15 + 16] = f2bf(o1 * scale);
        outp[l15 + 32] = f2bf(o2 * scale);
        outp[l15 + 48] = f2bf(o3 * scale);
        if (l15 == 0) (qk ? y2k : x2q)[h * N + n] = fn * fn;
    }
}

// K2: fused attention: QK^T + dist/exp -> LDS P tile -> PV + ones-MFMA
// row-sum -> normalized aout. Block = (16-row tile rt, head h): 256 blocks.
// FIX vs R13: phase 2 reads P in 32-wide chunks, so the written range is
// padded to an EVEN number of 16-tiles; pad tiles are explicit zeros
// (uninitialized LDS in the 32-alignment overhang was the NaN source).
__global__ __launch_bounds__(256, 4) void k_attn(
        const unsigned short* __restrict__ qh, const unsigned short* __restrict__ kh,
        const unsigned short* __restrict__ vt,
        const float* __restrict__ x2q, const float* __restrict__ y2k,
        const float* __restrict__ c_logits, const float* __restrict__ geo_scale,
        unsigned short* __restrict__ aout) {
    const int N = 512;
    int rt = blockIdx.x, h = blockIdx.y;
    int r0 = rt * 16;
    int kend = r0 + 16;
    int tid = threadIdx.x;
    int wv = tid >> 6, lane = tid & 63, l15 = lane & 15, kb = lane >> 4;
    __shared__ __align__(16) unsigned short Ps[16][520];   // stride 1040B

    float c = log1pf(expf(c_logits[h]));
    float sqc = fmaxf(sqrtf(c), EPSF);
    float gs = geo_scale[h];

    // ---- Phase 1: S tiles -> dist/exp -> LDS (zero-padded to even tiles) ----
    const unsigned short* qb = qh + ((size_t)h * N + r0 + l15) * 64 + kb * 8;
    s16x8 aq0 = *(const s16x8*)(qb);
    s16x8 aq1 = *(const s16x8*)(qb + 32);
    float x2v[4], bv[4];
    #pragma unroll
    for (int r = 0; r < 4; ++r) {
        int qi = r0 + kb * 4 + r;
        x2v[r] = x2q[h * N + qi];
        bv[r] = 1.f - c * x2v[r];
    }
    int ntile = rt + 1;
    int ntile_pad = (ntile + 1) & ~1;      // even # of 16-col tiles
    for (int j = wv; j < ntile_pad; j += 4) {
        if (j < ntile) {
            const unsigned short* kbp = kh + ((size_t)h * N + j * 16 + l15) * 64 + kb * 8;
            f32x4 s = {};
            s = __builtin_amdgcn_mfma_f32_16x16x32_bf16(aq0, *(const s16x8*)(kbp), s, 0, 0, 0);
            s = __builtin_amdgcn_mfma_f32_16x16x32_bf16(aq1, *(const s16x8*)(kbp + 32), s, 0, 0, 0);
            int ki = j * 16 + l15;
            float y2 = y2k[h * N + ki];
            #pragma unroll
            for (int r = 0; r < 4; ++r) {
                int qi = r0 + kb * 4 + r;
                float dot = s[r];
                float x2 = x2v[r], b_ = bv[r];
                float a_ = 1.f + c * (y2 - 2.f * dot);
                float num2 = a_ * a_ * x2 + b_ * b_ * y2 - 2.f * a_ * b_ * dot;
                float den = fmaxf(1.f - 2.f * c * dot + c * c * x2 * y2, EPSF);
                float nrm = sqrtf(fmaxf(num2, 0.f)) / den;
                if (nrm >= 1.f) nrm = 1.f - EPSF;
                float arg = fminf(sqc * nrm, 1.f - EPSF);
                float sv = -gs * (2.f * atanhf(arg) / sqc);
                float pe = (ki <= qi) ? expf(sv) : 0.f;
                Ps[kb * 4 + r][j * 16 + l15] = f2bf(pe);
            }
        } else {
            #pragma unroll
            for (int r = 0; r < 4; ++r)
                Ps[kb * 4 + r][j * 16 + l15] = 0;
        }
    }
    __syncthreads();

    // ---- Phase 2: O = P@V + ones-MFMA row-sum ----
    s16x8 ones;
    #pragma unroll
    for (int i = 0; i < 8; ++i) ones[i] = (short)0x3F80;   // bf16 1.0
    int d0 = wv * 16;
    const unsigned short* Vb = vt + ((size_t)(h * 64 + d0 + l15)) * N + kb * 8;
    f32x4 acc = {};
    f32x4 acc_s = {};
    for (int k0 = 0; k0 < kend; k0 += 32) {
        s16x8 a = *(const s16x8*)(&Ps[l15][k0 + kb * 8]);
        s16x8 b = *(const s16x8*)(Vb + k0);
        acc = __builtin_amdgcn_mfma_f32_16x16x32_bf16(a, b, acc, 0, 0, 0);
        acc_s = __builtin_amdgcn_mfma_f32_16x16x32_bf16(a, ones, acc_s, 0, 0, 0);
    }
    #pragma unroll
    for (int r = 0; r < 4; ++r) {
        int qi = r0 + kb * 4 + r;
        float il = 1.f / acc_s[r];
        aout[(size_t)qi * 512 + h * 64 + d0 + l15] = f2bf(acc[r] * il);
    }
}

// K3: out = aout(bf16) @ W_out + b. 16x16 tiles, W gathered fp32->bf16.
__global__ __launch_bounds__(256, 4) void k_out(
        const unsigned short* __restrict__ A, const float* __restrict__ W,
        const float* __restrict__ bias, float* __restrict__ C) {
    const int K = 512, NN = 512;
    int tid = threadIdx.x;
    int wv = tid >> 6, lane = tid & 63, l15 = lane & 15, kb = lane >> 4;
    int wr = blockIdx.x / 8;
    int cg = blockIdx.x % 8;
    int col0 = cg * 64 + wv * 16;
    const unsigned short* Ab = A + (size_t)(wr * 16 + l15) * K + kb * 8;
    f32x4 acc = {};
    #pragma unroll 4
    for (int k0 = 0; k0 < K; k0 += 32) {
        s16x8 a = *(const s16x8*)(Ab + k0);
        s16x8 b;
        #pragma unroll
        for (int t = 0; t < 8; ++t)
            b[t] = (short)f2bf(W[(size_t)(k0 + kb * 8 + t) * NN + col0 + l15]);
        acc = __builtin_amdgcn_mfma_f32_16x16x32_bf16(a, b, acc, 0, 0, 0);
    }
    int col = col0 + l15;
    float bv = bias[col];
    #pragma unroll
    for (int r = 0; r < 4; ++r)
        C[(size_t)(wr * 16 + kb * 4 + r) * NN + col] = acc[r] + bv;
}

extern "C" void kernel_launch(void* const* d_in, const int* in_sizes, int n_in,
                              void* d_out, int out_size, void* d_ws, size_t ws_size,
                              hipStream_t stream) {
    const float* x_hyp     = (const float*)d_in[0];
    const float* freqs     = (const float*)d_in[1];
    const float* c_sphere  = (const float*)d_in[2];
    const float* w_qkv     = (const float*)d_in[3];
    const float* b_qkv     = (const float*)d_in[4];
    const float* w_out     = (const float*)d_in[5];
    const float* b_out     = (const float*)d_in[6];
    const float* c_logits  = (const float*)d_in[7];
    const float* geo_scale = (const float*)d_in[8];
    float* out = (float*)d_out;

    const int H = 8;
    char* base = (char*)d_ws;
    unsigned short* qh16   = (unsigned short*)base;    base += 512 * 1024;
    unsigned short* kh16   = (unsigned short*)base;    base += 512 * 1024;
    unsigned short* vt16   = (unsigned short*)base;    base += 512 * 1024;
    unsigned short* aout16 = (unsigned short*)base;    base += 512 * 1024;
    float*          x2q    = (float*)base;             base += 16 * 1024;
    float*          y2k    = (float*)base;             base += 16 * 1024;

    k_qkv_rope<<<256, 256, 0, stream>>>(x_hyp, w_qkv, b_qkv, c_sphere, freqs,
                                        c_logits, qh16, kh16, vt16, x2q, y2k);
    k_attn<<<dim3(32, H), 256, 0, stream>>>(qh16, kh16, vt16, x2q, y2k,
                                            c_logits, geo_scale, aout16);
    k_out<<<256, 256, 0, stream>>>(aout16, w_out, b_out, out);
}